// Round 4
// baseline (211.892 us; speedup 1.0000x reference)
//
#include <hip/hip_runtime.h>
#include <math.h>

#define S_LEN 8192
#define HDIM  4096
#define H4    (HDIM / 4)      // 1024 float4 per row
#define P1_BLOCK 512
#define P1_WAVES 8
#define RB 8                  // rows per barrier batch in pass1
#define SUMB 32               // finalize: column-sum blocks (32 float4-cols each)
#define FB_ATTN 8             // 8 blocks * 256 thr * 4 = 8192 attn elements

__device__ __forceinline__ float wave_reduce_sum(float x) {
#pragma unroll
  for (int o = 32; o > 0; o >>= 1) x += __shfl_xor(x, o, 64);
  return x;
}
__device__ __forceinline__ float wave_reduce_max(float x) {
#pragma unroll
  for (int o = 32; o > 0; o >>= 1) x = fmaxf(x, __shfl_xor(x, o, 64));
  return x;
}

// Fused GEMV + online softmax + weighted row accumulation.
// RB=8 rows per barrier pair: 16 dwordx4 in flight per lane per drain.
__global__ __launch_bounds__(P1_BLOCK) void pass1_k(
    const float* __restrict__ enc, const float* __restrict__ hidden,
    float* __restrict__ energies, float* __restrict__ mb, float* __restrict__ lb,
    float* __restrict__ opart, int rpb) {
  const int t = threadIdx.x;
  const int b = blockIdx.x;
  const int row0 = b * rpb;
  const int row1 = min(S_LEN, row0 + rpb);

  const float4* hv = (const float4*)hidden;
  float hh[8];
  {
    const float4 h0 = hv[t];
    const float4 h1 = hv[t + P1_BLOCK];
    hh[0] = h0.x; hh[1] = h0.y; hh[2] = h0.z; hh[3] = h0.w;
    hh[4] = h1.x; hh[5] = h1.y; hh[6] = h1.z; hh[7] = h1.w;
  }

  float aa[8] = {0.f, 0.f, 0.f, 0.f, 0.f, 0.f, 0.f, 0.f};
  float m = -INFINITY, l = 0.f;

  __shared__ float red[RB * P1_WAVES];
  const int wid = t >> 6;
  const bool lane0 = (t & 63) == 0;
  const float4* encv = (const float4*)enc;

  for (int r0 = row0; r0 < row1; r0 += RB) {
    const int nr = min(RB, row1 - r0);
    float vv[RB][8];
    float d[RB];
#pragma unroll
    for (int r = 0; r < RB; ++r) {
      float4 x0 = make_float4(0.f, 0.f, 0.f, 0.f);
      float4 x1 = make_float4(0.f, 0.f, 0.f, 0.f);
      if (r < nr) {
        const float4* rp = encv + (size_t)(r0 + r) * H4;
        x0 = rp[t];
        x1 = rp[t + P1_BLOCK];
      }
      vv[r][0] = x0.x; vv[r][1] = x0.y; vv[r][2] = x0.z; vv[r][3] = x0.w;
      vv[r][4] = x1.x; vv[r][5] = x1.y; vv[r][6] = x1.z; vv[r][7] = x1.w;
    }
#pragma unroll
    for (int r = 0; r < RB; ++r) {
      float s = 0.f;
#pragma unroll
      for (int k = 0; k < 8; ++k) s = fmaf(vv[r][k], hh[k], s);
      d[r] = s;
    }
    // RB independent wave reductions, interleaved shuffle chains
#pragma unroll
    for (int o = 32; o > 0; o >>= 1) {
#pragma unroll
      for (int r = 0; r < RB; ++r) d[r] += __shfl_xor(d[r], o, 64);
    }
    if (lane0) {
#pragma unroll
      for (int r = 0; r < RB; ++r) red[r * P1_WAVES + wid] = d[r];
    }
    __syncthreads();
    float e[RB];
#pragma unroll
    for (int r = 0; r < RB; ++r) {
      const float4 q0 = *(const float4*)&red[r * P1_WAVES];
      const float4 q1 = *(const float4*)&red[r * P1_WAVES + 4];
      e[r] = (q0.x + q0.y + q0.z + q0.w) + (q1.x + q1.y + q1.z + q1.w);
    }
    __syncthreads();  // protect red[] before next batch overwrites
    if (t == 0) {
      for (int r = 0; r < nr; ++r) energies[r0 + r] = e[r];
    }
    // batched online-softmax update: one rescale per RB rows
    float mn = m;
#pragma unroll
    for (int r = 0; r < RB; ++r)
      if (r < nr) mn = fmaxf(mn, e[r]);
    const float sc = __expf(m - mn);  // m=-inf first batch -> 0; acc/l are 0
    float w[RB];
    float lsum = 0.f;
#pragma unroll
    for (int r = 0; r < RB; ++r) {
      w[r] = (r < nr) ? __expf(e[r] - mn) : 0.f;
      lsum += w[r];
    }
    l = l * sc + lsum;
#pragma unroll
    for (int k = 0; k < 8; ++k) {
      float a = aa[k] * sc;
#pragma unroll
      for (int r = 0; r < RB; ++r) a = fmaf(w[r], vv[r][k], a);
      aa[k] = a;
    }
    m = mn;
  }

  float4* op = (float4*)(opart + (size_t)b * HDIM);
  op[t]            = make_float4(aa[0], aa[1], aa[2], aa[3]);
  op[t + P1_BLOCK] = make_float4(aa[4], aa[5], aa[6], aa[7]);
  if (t == 0) { mb[b] = m; lb[b] = l; }
}

// blocks [0,SUMB): block j privately sums weighted partials for float4-cols
//   [j*32, j*32+32) over all g — no atomics, each out element written once.
// blocks [SUMB, SUMB+FB_ATTN): attn = exp(e - gm)/L, float4.
// Every block recomputes (gm, invL) locally from mb/lb (L2-hot, 4 KB).
__global__ __launch_bounds__(256) void finalize_k(
    const float* __restrict__ opart, const float* __restrict__ mb,
    const float* __restrict__ lb, const float* __restrict__ energies,
    float* __restrict__ out, int Gu) {
  const int t = threadIdx.x;
  const int wid = t >> 6;
  const bool lane0 = (t & 63) == 0;
  __shared__ float smax[4], ssum[4];

  float mv = -INFINITY;
  for (int g = t; g < Gu; g += 256) mv = fmaxf(mv, mb[g]);
  mv = wave_reduce_max(mv);
  if (lane0) smax[wid] = mv;
  __syncthreads();
  const float gm = fmaxf(fmaxf(smax[0], smax[1]), fmaxf(smax[2], smax[3]));

  float lv = 0.f;
  for (int g = t; g < Gu; g += 256) lv += lb[g] * __expf(mb[g] - gm);
  lv = wave_reduce_sum(lv);
  if (lane0) ssum[wid] = lv;
  __syncthreads();
  const float invL = 1.f / (ssum[0] + ssum[1] + ssum[2] + ssum[3]);

  if ((int)blockIdx.x < SUMB) {
    const int c  = blockIdx.x * 32 + (t & 31);  // float4-column 0..1023
    const int g0 = t >> 5;                      // 8 g-groups
    float4 acc = {0.f, 0.f, 0.f, 0.f};
    for (int g = g0; g < Gu; g += 8) {
      const float w = __expf(mb[g] - gm) * invL;
      const float4 v = ((const float4*)opart)[(size_t)g * H4 + c];
      acc.x = fmaf(w, v.x, acc.x);
      acc.y = fmaf(w, v.y, acc.y);
      acc.z = fmaf(w, v.z, acc.z);
      acc.w = fmaf(w, v.w, acc.w);
    }
    __shared__ float4 sred[256];
    sred[t] = acc;
    __syncthreads();
    if (t < 32) {
      float4 s = sred[t];
#pragma unroll
      for (int q = 1; q < 8; ++q) {
        const float4 v = sred[q * 32 + t];
        s.x += v.x; s.y += v.y; s.z += v.z; s.w += v.w;
      }
      ((float4*)out)[blockIdx.x * 32 + t] = s;
    }
  } else {
    const int i4 = ((int)blockIdx.x - SUMB) * 256 + t;  // float4 idx into [0,2048)
    const float4 e = ((const float4*)energies)[i4];
    float4 a;
    a.x = __expf(e.x - gm) * invL;
    a.y = __expf(e.y - gm) * invL;
    a.z = __expf(e.z - gm) * invL;
    a.w = __expf(e.w - gm) * invL;
    ((float4*)(out + HDIM))[i4] = a;
  }
}

extern "C" void kernel_launch(void* const* d_in, const int* in_sizes, int n_in,
                              void* d_out, int out_size, void* d_ws, size_t ws_size,
                              hipStream_t stream) {
  const float* hidden = (const float*)d_in[0];          // [4096] f32
  const float* enc    = (const float*)d_in[1];          // [8192,1,4096] f32
  float* out = (float*)d_out;                           // [4096 output | 8192 attn]
  float* wsf = (float*)d_ws;

  // workspace layout (floats):
  float* energies = wsf;            // 8192
  float* mb       = wsf + 8192;     // up to 1024
  float* lb       = wsf + 9216;     // up to 1024
  float* opart    = wsf + 10240;    // G * 4096

  const size_t avail_f = ws_size / 4;
  int Gmax = (avail_f > 10240) ? (int)((avail_f - 10240) / HDIM) : 1;
  int G = Gmax < 512 ? Gmax : 512;
  if (G < 1) G = 1;
  const int rpb = (S_LEN + G - 1) / G;
  const int Gu  = (S_LEN + rpb - 1) / rpb;   // blocks actually used, all non-empty

  pass1_k<<<Gu, P1_BLOCK, 0, stream>>>(enc, hidden, energies, mb, lb, opart, rpb);
  finalize_k<<<SUMB + FB_ATTN, 256, 0, stream>>>(opart, mb, lb, energies, out, Gu);
}